// Round 12
// baseline (71.995 us; speedup 1.0000x reference)
//
#include <hip/hip_runtime.h>
#include <hip/hip_bf16.h>

// AdaptiveFourierPositionEncoding — round 12: r11 + prologue amortization.
// 4 tiles per wave (1024 blocks): W-staging L2 traffic 134->33 MB and the
// per-block prologue cost /4. In-loop pipeline keeps the single wave-private
// sbuf: linear readback -> lgkmcnt(0) -> issue NEXT tile's global_load_lds
// (loads BEFORE stores) -> issue coalesced stores -> s_waitcnt vmcnt(8)
// (retires exactly the 8 loads; stores stay in flight). No store->load
// drain ever happens (the r2/r3/r6 trap).

#define NTOK  (8 * 32768)
#define NTILE (NTOK / 16)             // 16384
#define WPB   4
#define TPW   4
#define NBLK  (NTILE / (WPB * TPW))   // 1024

typedef short  bf16x8 __attribute__((ext_vector_type(8)));
typedef float  f32x4  __attribute__((ext_vector_type(4)));

static __device__ __forceinline__ short f2bf(float f) {
    __hip_bfloat16 h = __float2bfloat16(f);   // RNE
    return __builtin_bit_cast(short, h);
}

// Stage one 16x128 f32 tile: 8 x global_load_lds dwordx4, LDS dest linear,
// source XOR-pre-swizzled (logical granule (t,u) -> slot t*32 + (u^(t&7))).
static __device__ __forceinline__ void stage_tile(const char* __restrict__ xtile,
                                                  char* sb, int lane) {
    #pragma unroll
    for (int j = 0; j < 8; ++j) {
        const int g = 64 * j + lane;           // LDS slot index
        const int t = g >> 5;                  // token row
        const int u = (g & 31) ^ (t & 7);      // logical granule in row
        __builtin_amdgcn_global_load_lds(
            (const __attribute__((address_space(1))) void*)(xtile + t * 512 + u * 16),
            (__attribute__((address_space(3))) void*)(sb + j * 1024),
            16, 0, 0);
    }
}

__global__ __launch_bounds__(256, 3) void afpe_r12(
    const float* __restrict__ x, const int* __restrict__ pos,
    const float* __restrict__ fb, const float* __restrict__ ph,
    const float* __restrict__ aw, const float* __restrict__ ab,
    float* __restrict__ out)
{
    // W fragments, fragment-linear: chunk(m,c) @ (m*4+c)*1024 + lane*16.
    __shared__ __align__(16) char wlds[16384];
    __shared__ __align__(16) char sbuf[4][8192];   // per-wave stage + transpose
    __shared__ float pfb[64], pph[64], pab[64];

    const int tid  = threadIdx.x;
    const int lane = tid & 63;
    const int wv   = tid >> 6;
    const int q    = lane >> 4;     // k-group / D-row group
    const int tt   = lane & 15;     // token-in-tile / A-row

    // ---- one-time staging: W -> bf16 frags in LDS, params -> LDS ----
    #pragma unroll
    for (int g0 = 0; g0 < 4; ++g0) {
        const int g  = g0 * 256 + tid;          // granule 0..1023
        const int mc = g >> 6, l = g & 63;
        const int sm = mc >> 2, sc = mc & 3, sq = l >> 4, st = l & 15;
        const float* wp = aw + (size_t)(16 * sm + st) * 128 + sq * 8 + 32 * sc;
        const float4 w0 = *(const float4*)wp;
        const float4 w1 = *(const float4*)(wp + 4);
        bf16x8 a;
        a[0] = f2bf(w0.x); a[1] = f2bf(w0.y); a[2] = f2bf(w0.z); a[3] = f2bf(w0.w);
        a[4] = f2bf(w1.x); a[5] = f2bf(w1.y); a[6] = f2bf(w1.z); a[7] = f2bf(w1.w);
        *(bf16x8*)(wlds + mc * 1024 + l * 16) = a;
    }
    if (tid < 64) { pfb[tid] = fb[tid]; pph[tid] = ph[tid]; pab[tid] = ab[tid]; }
    __syncthreads();

    // ---- 4 contiguous tiles per wave ----
    const int tbase = (blockIdx.x * WPB + wv) * TPW;
    char* sb = sbuf[wv];

    // prologue: pos for all tiles, then stage tile 0, drain everything once
    int pv[TPW];
    #pragma unroll
    for (int s = 0; s < TPW; ++s) pv[s] = pos[(tbase + s) * 16 + tt];
    stage_tile((const char*)(x + (size_t)tbase * 2048), sb, lane);
    asm volatile("s_waitcnt vmcnt(0)" ::: "memory");

    #pragma unroll
    for (int it = 0; it < TPW; ++it) {
        const int tile = tbase + it;

        // x fragments from LDS: lane (q,tt), granule u = 2q + 8c + h
        float4 xf[8];
        #pragma unroll
        for (int c = 0; c < 4; ++c) {
            #pragma unroll
            for (int h = 0; h < 2; ++h) {
                const int u = 2 * q + 8 * c + h;
                xf[2 * c + h] = *(const float4*)(sb + tt * 512 + (u ^ (tt & 7)) * 16);
            }
        }

        // logits: acc[m] reg r = logit[band 16m + 4q + r][token tt]
        f32x4 acc[4];
        #pragma unroll
        for (int m = 0; m < 4; ++m) {
            const float4 abv = *(const float4*)&pab[16 * m + 4 * q];
            acc[m][0] = abv.x; acc[m][1] = abv.y; acc[m][2] = abv.z; acc[m][3] = abv.w;
        }
        #pragma unroll
        for (int c = 0; c < 4; ++c) {
            const float4 b0 = xf[2 * c], b1 = xf[2 * c + 1];
            bf16x8 B;
            B[0] = f2bf(b0.x); B[1] = f2bf(b0.y); B[2] = f2bf(b0.z); B[3] = f2bf(b0.w);
            B[4] = f2bf(b1.x); B[5] = f2bf(b1.y); B[6] = f2bf(b1.z); B[7] = f2bf(b1.w);
            #pragma unroll
            for (int m = 0; m < 4; ++m) {
                const bf16x8 A = *(const bf16x8*)(wlds + (m * 4 + c) * 1024 + lane * 16);
                acc[m] = __builtin_amdgcn_mfma_f32_16x16x32_bf16(A, B, acc[m], 0, 0, 0);
            }
        }

        // softmax over 64 bands of token tt (partners: lanes tt + 16k)
        float e[4][4];
        float s = 0.f;
        #pragma unroll
        for (int m = 0; m < 4; ++m) {
            #pragma unroll
            for (int r = 0; r < 4; ++r) { e[m][r] = __expf(acc[m][r]); s += e[m][r]; }
        }
        s += __shfl_xor(s, 16, 64);
        s += __shfl_xor(s, 32, 64);
        const float rinv = 1.0f / s;

        // trig + epilogue -> ds_write swizzled back into sbuf (lane overwrites
        // exactly the slots it read; same-wave DS ops are in-order)
        const float pf = (float)pv[it];
        #pragma unroll
        for (int c = 0; c < 4; ++c) {
            const float4 fq4 = *(const float4*)&pfb[16 * c + 4 * q];
            const float4 ph4 = *(const float4*)&pph[16 * c + 4 * q];
            const float fq[4] = {fq4.x, fq4.y, fq4.z, fq4.w};
            const float pq[4] = {ph4.x, ph4.y, ph4.z, ph4.w};
            float sa[4], ca[4];
            #pragma unroll
            for (int r = 0; r < 4; ++r) {
                float ang = pf * fq[r];
                ang = ang + pq[r];
                double td = (double)ang * 0.15915494309189535;  // 1/(2*pi)
                td -= floor(td);
                const float rev = (float)td;
                const float at  = e[c][r] * rinv;
                sa[r] = __builtin_amdgcn_sinf(rev) * at;
                ca[r] = __builtin_amdgcn_cosf(rev) * at;
            }
            const float4 xv0 = xf[2 * c], xv1 = xf[2 * c + 1];
            f32x4 o0, o1;
            o0[0] = xv0.x + sa[0]; o0[1] = xv0.y + ca[0];
            o0[2] = xv0.z + sa[1]; o0[3] = xv0.w + ca[1];
            o1[0] = xv1.x + sa[2]; o1[1] = xv1.y + ca[2];
            o1[2] = xv1.z + sa[3]; o1[3] = xv1.w + ca[3];
            const int u0 = 2 * q + 8 * c;
            *(f32x4*)(sb + tt * 512 + ((u0)     ^ (tt & 7)) * 16) = o0;
            *(f32x4*)(sb + tt * 512 + ((u0 + 1) ^ (tt & 7)) * 16) = o1;
        }

        // linear readback into registers (full rows)
        f32x4 vout[8];
        #pragma unroll
        for (int j = 0; j < 8; ++j) {
            const int g  = 64 * j + lane;
            const int t  = g >> 5;
            const int up = g & 31;
            vout[j] = *(const f32x4*)(sb + t * 512 + (up ^ (t & 7)) * 16);
        }
        asm volatile("s_waitcnt lgkmcnt(0)" ::: "memory");
        __builtin_amdgcn_sched_barrier(0);

        // issue NEXT tile's staging loads first (oldest in vmcnt order)...
        if (it < TPW - 1)
            stage_tile((const char*)(x + (size_t)(tile + 1) * 2048), sb, lane);
        __builtin_amdgcn_sched_barrier(0);

        // ...then the coalesced stores (2 full 512B rows per instruction)
        float* ob = out + (size_t)tile * 2048;
        #pragma unroll
        for (int j = 0; j < 8; ++j) {
            const int g  = 64 * j + lane;
            const int t  = g >> 5;
            const int up = g & 31;
            *(f32x4*)(ob + t * 128 + up * 4) = vout[j];
        }
        __builtin_amdgcn_sched_barrier(0);

        // retire exactly the 8 staging loads; stores stay in flight
        if (it < TPW - 1)
            asm volatile("s_waitcnt vmcnt(8)" ::: "memory");
    }
}

extern "C" void kernel_launch(void* const* d_in, const int* in_sizes, int n_in,
                              void* d_out, int out_size, void* d_ws, size_t ws_size,
                              hipStream_t stream) {
    const float* x   = (const float*)d_in[0];
    const int*   pos = (const int*)d_in[1];
    const float* fb  = (const float*)d_in[2];
    const float* ph  = (const float*)d_in[3];
    const float* aw  = (const float*)d_in[4];
    const float* ab  = (const float*)d_in[5];
    float* out = (float*)d_out;

    // 1024 blocks x 4 waves; each wave owns 4 contiguous 16-token tiles.
    afpe_r12<<<NBLK, 256, 0, stream>>>(x, pos, fb, ph, aw, ab, out);
}

// Round 13
// 46.538 us; speedup vs baseline: 1.5470x; 1.5470x over previous
//
#include <hip/hip_runtime.h>
#include <hip/hip_bf16.h>

// AdaptiveFourierPositionEncoding — round 13: r11 byte-for-byte, ONE change:
// non-temporal flag on the final coalesced stores. r9's nt test was
// invalidated by partial-line fragmentation (WRITE 131->197MB); now each
// store instruction writes 1KB contiguous (8 full 128B lines), so nt can
// stream to HBM without allocating in L2/L3 -> x stays L3-resident.

#define NTOK  (8 * 32768)
#define NTILE (NTOK / 16)     // 16384
#define WPB   4
#define NBLK  (NTILE / WPB)   // 4096

typedef short  bf16x8 __attribute__((ext_vector_type(8)));
typedef float  f32x4  __attribute__((ext_vector_type(4)));

static __device__ __forceinline__ short f2bf(float f) {
    __hip_bfloat16 h = __float2bfloat16(f);   // RNE
    return __builtin_bit_cast(short, h);
}

__global__ __launch_bounds__(256, 3) void afpe_r13(
    const float* __restrict__ x, const int* __restrict__ pos,
    const float* __restrict__ fb, const float* __restrict__ ph,
    const float* __restrict__ aw, const float* __restrict__ ab,
    float* __restrict__ out)
{
    // W fragments, fragment-linear: chunk(m,c) @ (m*4+c)*1024 + lane*16.
    __shared__ __align__(16) char wlds[16384];
    __shared__ __align__(16) char sbuf[4][8192];   // per-wave x-stage + transpose
    __shared__ float pfb[64], pph[64], pab[64];

    const int tid  = threadIdx.x;
    const int lane = tid & 63;
    const int wv   = tid >> 6;
    const int q    = lane >> 4;     // k-group / D-row group
    const int tt   = lane & 15;     // token-in-tile / A-row

    // ---- one-time staging: W -> bf16 frags in LDS, params -> LDS ----
    #pragma unroll
    for (int g0 = 0; g0 < 4; ++g0) {
        const int g  = g0 * 256 + tid;          // granule 0..1023
        const int mc = g >> 6, l = g & 63;
        const int sm = mc >> 2, sc = mc & 3, sq = l >> 4, st = l & 15;
        const float* wp = aw + (size_t)(16 * sm + st) * 128 + sq * 8 + 32 * sc;
        const float4 w0 = *(const float4*)wp;
        const float4 w1 = *(const float4*)(wp + 4);
        bf16x8 a;
        a[0] = f2bf(w0.x); a[1] = f2bf(w0.y); a[2] = f2bf(w0.z); a[3] = f2bf(w0.w);
        a[4] = f2bf(w1.x); a[5] = f2bf(w1.y); a[6] = f2bf(w1.z); a[7] = f2bf(w1.w);
        *(bf16x8*)(wlds + mc * 1024 + l * 16) = a;
    }
    if (tid < 64) { pfb[tid] = fb[tid]; pph[tid] = ph[tid]; pab[tid] = ab[tid]; }
    __syncthreads();

    // ---- one tile per wave ----
    const int tile = blockIdx.x * WPB + wv;
    const char* xtile = (const char*)(x + (size_t)tile * 2048);
    char* sb = sbuf[wv];

    // stage x-tile: 8 x global_load_lds dwordx4; logical granule (t,u) of
    // the 16x128 tile lands at LDS slot t*32 + (u ^ (t&7)). Source is
    // pre-swizzled so each instruction reads 2 complete 512B rows.
    #pragma unroll
    for (int j = 0; j < 8; ++j) {
        const int g = 64 * j + lane;           // LDS slot index
        const int t = g >> 5;                  // token row
        const int u = (g & 31) ^ (t & 7);      // logical granule in row
        __builtin_amdgcn_global_load_lds(
            (const __attribute__((address_space(1))) void*)(xtile + t * 512 + u * 16),
            (__attribute__((address_space(3))) void*)(sb + j * 1024),
            16, 0, 0);
    }
    const int p = pos[tile * 16 + tt];
    asm volatile("s_waitcnt vmcnt(0)" ::: "memory");

    // x fragments from LDS: lane (q,tt), granule u = 2q + 8c + h
    float4 xf[8];
    #pragma unroll
    for (int c = 0; c < 4; ++c) {
        #pragma unroll
        for (int h = 0; h < 2; ++h) {
            const int u = 2 * q + 8 * c + h;
            xf[2 * c + h] = *(const float4*)(sb + tt * 512 + (u ^ (tt & 7)) * 16);
        }
    }

    // logits: acc[m] reg r = logit[band 16m + 4q + r][token tt]
    f32x4 acc[4];
    #pragma unroll
    for (int m = 0; m < 4; ++m) {
        const float4 abv = *(const float4*)&pab[16 * m + 4 * q];
        acc[m][0] = abv.x; acc[m][1] = abv.y; acc[m][2] = abv.z; acc[m][3] = abv.w;
    }
    #pragma unroll
    for (int c = 0; c < 4; ++c) {
        const float4 b0 = xf[2 * c], b1 = xf[2 * c + 1];
        bf16x8 B;
        B[0] = f2bf(b0.x); B[1] = f2bf(b0.y); B[2] = f2bf(b0.z); B[3] = f2bf(b0.w);
        B[4] = f2bf(b1.x); B[5] = f2bf(b1.y); B[6] = f2bf(b1.z); B[7] = f2bf(b1.w);
        #pragma unroll
        for (int m = 0; m < 4; ++m) {
            const bf16x8 A = *(const bf16x8*)(wlds + (m * 4 + c) * 1024 + lane * 16);
            acc[m] = __builtin_amdgcn_mfma_f32_16x16x32_bf16(A, B, acc[m], 0, 0, 0);
        }
    }

    // softmax over 64 bands of token tt (partners: lanes tt + 16k)
    float e[4][4];
    float s = 0.f;
    #pragma unroll
    for (int m = 0; m < 4; ++m) {
        #pragma unroll
        for (int r = 0; r < 4; ++r) { e[m][r] = __expf(acc[m][r]); s += e[m][r]; }
    }
    s += __shfl_xor(s, 16, 64);
    s += __shfl_xor(s, 32, 64);
    const float rinv = 1.0f / s;

    // trig + epilogue -> ds_write back into sbuf (same slot mapping; same-wave
    // LDS ops are in-order so the x-frag reads above are safe)
    const float pf = (float)p;
    #pragma unroll
    for (int c = 0; c < 4; ++c) {
        const float4 fq4 = *(const float4*)&pfb[16 * c + 4 * q];
        const float4 ph4 = *(const float4*)&pph[16 * c + 4 * q];
        const float fq[4] = {fq4.x, fq4.y, fq4.z, fq4.w};
        const float pq[4] = {ph4.x, ph4.y, ph4.z, ph4.w};
        float sa[4], ca[4];
        #pragma unroll
        for (int r = 0; r < 4; ++r) {
            float ang = pf * fq[r];
            ang = ang + pq[r];
            double td = (double)ang * 0.15915494309189535;  // 1/(2*pi)
            td -= floor(td);
            const float rev = (float)td;
            const float at  = e[c][r] * rinv;
            sa[r] = __builtin_amdgcn_sinf(rev) * at;
            ca[r] = __builtin_amdgcn_cosf(rev) * at;
        }
        const float4 xv0 = xf[2 * c], xv1 = xf[2 * c + 1];
        f32x4 o0, o1;
        o0[0] = xv0.x + sa[0]; o0[1] = xv0.y + ca[0];
        o0[2] = xv0.z + sa[1]; o0[3] = xv0.w + ca[1];
        o1[0] = xv1.x + sa[2]; o1[1] = xv1.y + ca[2];
        o1[2] = xv1.z + sa[3]; o1[3] = xv1.w + ca[3];
        const int u0 = 2 * q + 8 * c;
        *(f32x4*)(sb + tt * 512 + ((u0)     ^ (tt & 7)) * 16) = o0;
        *(f32x4*)(sb + tt * 512 + ((u0 + 1) ^ (tt & 7)) * 16) = o1;
    }

    // read back linear, store 2 full 512B rows per instruction — nt stores
    // (full lines -> streamed to HBM, no L2/L3 allocation/pollution)
    float* ob = out + (size_t)tile * 2048;
    #pragma unroll
    for (int j = 0; j < 8; ++j) {
        const int g  = 64 * j + lane;
        const int t  = g >> 5;
        const int up = g & 31;
        const f32x4 v = *(const f32x4*)(sb + t * 512 + (up ^ (t & 7)) * 16);
        __builtin_nontemporal_store(v, (f32x4*)(ob + t * 128 + up * 4));
    }
}

extern "C" void kernel_launch(void* const* d_in, const int* in_sizes, int n_in,
                              void* d_out, int out_size, void* d_ws, size_t ws_size,
                              hipStream_t stream) {
    const float* x   = (const float*)d_in[0];
    const int*   pos = (const int*)d_in[1];
    const float* fb  = (const float*)d_in[2];
    const float* ph  = (const float*)d_in[3];
    const float* aw  = (const float*)d_in[4];
    const float* ab  = (const float*)d_in[5];
    float* out = (float*)d_out;

    // 4096 blocks x 256 threads = 16384 waves, one 16-token tile each.
    afpe_r13<<<NBLK, 256, 0, stream>>>(x, pos, fb, ph, aw, ab, out);
}